// Round 1
// baseline (522.435 us; speedup 1.0000x reference)
//
#include <hip/hip_runtime.h>

// ---------------------------------------------------------------------------
// cseft: out[n, s, d] = sum_h conv_w[h] * (1/(sqrt(Dh)*nItem)) *
//                        q_h[n] . (K_{h,s}^T V_{h,s})[:, d]
// Reassociated: no [H,N,N] score tensor. Pipeline:
//   1. qf = x @ W1          [4096,1024]
//   2. kf = y @ W2          [4096,1024]
//   3. vf = y @ W3          [4096,1024]
//   4. U[h*128+dp][s*128+d] = c_h*scale * sum_i kf[s*256+i][h*128+dp]*vf[s*256+i][h*128+d]
//   5. out = qf @ U         [4096,1024]x[1024,2048]
// Constants hardcoded: N=4096, K=512, HDh=1024, H=8, Dh=128, nItem=256, nSet=16
// ---------------------------------------------------------------------------

#define TM 64
#define TN 64
#define TK 16

__global__ __launch_bounds__(256)
void gemm_f32(const float* __restrict__ A, const float* __restrict__ B,
              float* __restrict__ C, int M, int N, int K) {
    // C[M,N] = A[M,K] @ B[K,N], all row-major, dims divisible by tile sizes.
    __shared__ float sA[TK][TM + 4];   // +4 keeps float4 alignment for reads
    __shared__ float sB[TK][TN];

    const int tid = threadIdx.x;
    const int tx = tid & 15;          // 0..15
    const int ty = tid >> 4;          // 0..15
    const int m0 = blockIdx.y * TM;
    const int n0 = blockIdx.x * TN;

    float acc[4][4] = {};

    for (int kt = 0; kt < K; kt += TK) {
        // stage A tile (64 rows x 16 k): one float4 per thread
        {
            const int r = tid >> 2;          // 0..63
            const int c = (tid & 3) * 4;     // 0,4,8,12
            const float4 a4 = *(const float4*)(A + (size_t)(m0 + r) * K + kt + c);
            sA[c + 0][r] = a4.x;
            sA[c + 1][r] = a4.y;
            sA[c + 2][r] = a4.z;
            sA[c + 3][r] = a4.w;
        }
        // stage B tile (16 k x 64 cols): one float4 per thread
        {
            const int r = tid >> 4;          // 0..15
            const int c = (tid & 15) * 4;    // 0..60
            *(float4*)(&sB[r][c]) = *(const float4*)(B + (size_t)(kt + r) * N + n0 + c);
        }
        __syncthreads();

        #pragma unroll
        for (int kk = 0; kk < TK; ++kk) {
            const float4 a4 = *(const float4*)(&sA[kk][ty * 4]);
            const float4 b4 = *(const float4*)(&sB[kk][tx * 4]);
            const float ra[4] = {a4.x, a4.y, a4.z, a4.w};
            const float rb[4] = {b4.x, b4.y, b4.z, b4.w};
            #pragma unroll
            for (int a = 0; a < 4; ++a)
                #pragma unroll
                for (int b = 0; b < 4; ++b)
                    acc[a][b] += ra[a] * rb[b];
        }
        __syncthreads();
    }

    #pragma unroll
    for (int a = 0; a < 4; ++a) {
        float4 o;
        o.x = acc[a][0]; o.y = acc[a][1]; o.z = acc[a][2]; o.w = acc[a][3];
        *(float4*)(C + (size_t)(m0 + ty * 4 + a) * N + n0 + tx * 4) = o;
    }
}

// U builder: grid = (nSet=16, H=8), block = 256 threads.
// Each block computes one 128x128 tile: T = K_{h,s}^T @ V_{h,s} over 256 items,
// scaled by conv_w[h] / (sqrt(128) * 256).
__global__ __launch_bounds__(256)
void build_u(const float* __restrict__ kf, const float* __restrict__ vf,
             const float* __restrict__ conv_w, float* __restrict__ U) {
    const int s = blockIdx.x;   // set  0..15
    const int h = blockIdx.y;   // head 0..7

    __shared__ float sK[32][128];
    __shared__ float sV[32][132];   // pad (multiple of 4) for alignment

    const int tid = threadIdx.x;
    const int tx = tid & 15;    // 0..15 -> d  (cols, V side)
    const int ty = tid >> 4;    // 0..15 -> dp (rows, K side)

    float acc[8][8] = {};

    const size_t rowbase = (size_t)s * 256 * 1024 + (size_t)h * 128;

    for (int i0 = 0; i0 < 256; i0 += 32) {
        // stage 32 items x 128 dims of K and V
        const int r = tid >> 3;            // 0..31
        const int cb = (tid & 7) * 16;     // 0,16,...,112
        const size_t g = rowbase + (size_t)(i0 + r) * 1024 + cb;
        #pragma unroll
        for (int u = 0; u < 4; ++u) {
            *(float4*)(&sK[r][cb + u * 4]) = *(const float4*)(kf + g + u * 4);
            *(float4*)(&sV[r][cb + u * 4]) = *(const float4*)(vf + g + u * 4);
        }
        __syncthreads();

        #pragma unroll 4
        for (int i = 0; i < 32; ++i) {
            float ra[8], rb[8];
            *(float4*)(&ra[0]) = *(const float4*)(&sK[i][ty * 8]);
            *(float4*)(&ra[4]) = *(const float4*)(&sK[i][ty * 8 + 4]);
            *(float4*)(&rb[0]) = *(const float4*)(&sV[i][tx * 8]);
            *(float4*)(&rb[4]) = *(const float4*)(&sV[i][tx * 8 + 4]);
            #pragma unroll
            for (int a = 0; a < 8; ++a)
                #pragma unroll
                for (int b = 0; b < 8; ++b)
                    acc[a][b] += ra[a] * rb[b];
        }
        __syncthreads();
    }

    const float scale = conv_w[h] * (0.08838834764831845f / 256.0f);

    // U is [1024 x 2048]: row = h*128 + dp, col = s*128 + d
    #pragma unroll
    for (int a = 0; a < 8; ++a) {
        const size_t row = (size_t)h * 128 + ty * 8 + a;
        #pragma unroll
        for (int b = 0; b < 8; b += 4) {
            float4 o;
            o.x = acc[a][b + 0] * scale;
            o.y = acc[a][b + 1] * scale;
            o.z = acc[a][b + 2] * scale;
            o.w = acc[a][b + 3] * scale;
            *(float4*)(U + row * 2048 + (size_t)s * 128 + tx * 8 + b) = o;
        }
    }
}

extern "C" void kernel_launch(void* const* d_in, const int* in_sizes, int n_in,
                              void* d_out, int out_size, void* d_ws, size_t ws_size,
                              hipStream_t stream) {
    const float* x  = (const float*)d_in[0];  // [4096, 512]
    const float* y  = (const float*)d_in[1];  // [4096, 512]
    const float* W1 = (const float*)d_in[2];  // [512, 1024]
    const float* W2 = (const float*)d_in[3];  // [512, 1024]
    const float* W3 = (const float*)d_in[4];  // [512, 1024]
    const float* cw = (const float*)d_in[5];  // [8]
    // d_in[6] = nItem (==256), constant -> hardcoded
    float* out = (float*)d_out;               // [4096, 16, 128]

    float* qf = (float*)d_ws;                 // 4096*1024
    float* kf = qf + (size_t)4096 * 1024;
    float* vf = kf + (size_t)4096 * 1024;
    float* U  = vf + (size_t)4096 * 1024;     // 1024*2048

    dim3 blk(256);

    dim3 g1(1024 / TN, 4096 / TM);
    hipLaunchKernelGGL(gemm_f32, g1, blk, 0, stream, x, W1, qf, 4096, 1024, 512);
    hipLaunchKernelGGL(gemm_f32, g1, blk, 0, stream, y, W2, kf, 4096, 1024, 512);
    hipLaunchKernelGGL(gemm_f32, g1, blk, 0, stream, y, W3, vf, 4096, 1024, 512);

    hipLaunchKernelGGL(build_u, dim3(16, 8), blk, 0, stream, kf, vf, cw, U);

    dim3 g5(2048 / TN, 4096 / TM);
    hipLaunchKernelGGL(gemm_f32, g5, blk, 0, stream, qf, U, out, 4096, 2048, 1024);
}

// Round 2
// 189.922 us; speedup vs baseline: 2.7508x; 2.7508x over previous
//
#include <hip/hip_runtime.h>
#include <stdint.h>
#include <stddef.h>

// ---------------------------------------------------------------------------
// cseft reassociated (no [H,N,N] scores):
//   1. xb = bf16(x), yb = bf16(y)
//   2. w{1,2,3}t = bf16(W^T)  [1024,512]
//   3. qb = xb@W1, kb = yb@W2, vb = yb@W3      (bf16 MFMA, bf16 out) [4096,1024]
//   4. Ut[s*128+d][h*128+dp] = cw[h]*scale * sum_i kb[i][h,dp]*vb[i][d]  (per set s)
//   5. out = qb @ Ut^T   (bf16 MFMA, fp32 out) [4096,2048]
// N=4096 K=512 H=8 Dh=128 nItem=256 nSet=16 hardcoded.
// ---------------------------------------------------------------------------

typedef short short8 __attribute__((ext_vector_type(8)));
typedef float f32x4 __attribute__((ext_vector_type(4)));

#define AS1 __attribute__((address_space(1)))
#define AS3 __attribute__((address_space(3)))

__device__ __forceinline__ void gl_lds16(const void* g, void* l) {
    __builtin_amdgcn_global_load_lds((AS1 void*)(uintptr_t)g, (AS3 void*)l, 16, 0, 0);
}

__device__ __forceinline__ short f2bf(float f) {
    union { float f; unsigned u; } v; v.f = f;
    unsigned r = v.u + 0x7FFFu + ((v.u >> 16) & 1u);
    return (short)(r >> 16);
}
__device__ __forceinline__ float bfbits2f(unsigned hi_bits) {
    union { unsigned u; float f; } v; v.u = hi_bits; return v.f;
}

// fp32 -> bf16, 8 elems/thread
__global__ __launch_bounds__(256)
void cvt_bf16(const float* __restrict__ in, short* __restrict__ out, int n8) {
    int i = blockIdx.x * 256 + threadIdx.x;
    if (i >= n8) return;
    const float4* p = (const float4*)in + (size_t)i * 2;
    float4 a = p[0], b = p[1];
    short8 o;
    o[0] = f2bf(a.x); o[1] = f2bf(a.y); o[2] = f2bf(a.z); o[3] = f2bf(a.w);
    o[4] = f2bf(b.x); o[5] = f2bf(b.y); o[6] = f2bf(b.z); o[7] = f2bf(b.w);
    *((short8*)out + i) = o;
}

// W[K][N] fp32 -> Wt[N][K] bf16.  block (32,8), grid (N/32, K/32)
__global__ __launch_bounds__(256)
void transpose_cvt(const float* __restrict__ W, short* __restrict__ Wt, int K, int N) {
    __shared__ float t[32][33];
    const int bx = blockIdx.x * 32, by = blockIdx.y * 32;
    const int tx = threadIdx.x, ty = threadIdx.y;
    #pragma unroll
    for (int j = 0; j < 4; ++j)
        t[ty + j * 8][tx] = W[(size_t)(by + ty + j * 8) * N + bx + tx];
    __syncthreads();
    #pragma unroll
    for (int j = 0; j < 4; ++j)
        Wt[(size_t)(bx + ty + j * 8) * K + by + tx] = f2bf(t[tx][ty + j * 8]);
}

// C[M,N] = A[M,K] * Bt[N,K]^T, bf16 in, fp32 accum. 128x128 tile, BK=32,
// 256 thr = 4 waves, each wave 64x64 via 4x4 of 16x16x32 MFMA.
template <bool BF16OUT>
__global__ __launch_bounds__(256)
void gemm_bt(const short* __restrict__ A, const short* __restrict__ Bt,
             void* __restrict__ Cout, int M, int N, int K) {
    __shared__ short sA[128 * 32];
    __shared__ short sB[128 * 32];

    const int tid = threadIdx.x;
    const int wave = tid >> 6, lane = tid & 63;
    const int quad = lane >> 4, ml = lane & 15;
    const int m0 = blockIdx.y * 128, n0 = blockIdx.x * 128;
    const int wm0 = (wave >> 1) * 64, wn0 = (wave & 1) * 64;
    // staging: chunk c covers rows 16c..16c+15; lane -> row 16c+(lane>>2), k-off (lane&3)*8
    const int srow = lane >> 2, skoff = (lane & 3) * 8;
    const int c0 = 2 * wave, c1 = 2 * wave + 1;

    f32x4 acc[4][4];
    #pragma unroll
    for (int i = 0; i < 4; ++i)
        #pragma unroll
        for (int j = 0; j < 4; ++j) {
            acc[i][j][0] = 0.f; acc[i][j][1] = 0.f;
            acc[i][j][2] = 0.f; acc[i][j][3] = 0.f;
        }

    for (int kt = 0; kt < K; kt += 32) {
        gl_lds16(A  + (size_t)(m0 + c0 * 16 + srow) * K + kt + skoff,
                 (char*)sA + c0 * 1024 + lane * 16);
        gl_lds16(A  + (size_t)(m0 + c1 * 16 + srow) * K + kt + skoff,
                 (char*)sA + c1 * 1024 + lane * 16);
        gl_lds16(Bt + (size_t)(n0 + c0 * 16 + srow) * K + kt + skoff,
                 (char*)sB + c0 * 1024 + lane * 16);
        gl_lds16(Bt + (size_t)(n0 + c1 * 16 + srow) * K + kt + skoff,
                 (char*)sB + c1 * 1024 + lane * 16);
        __syncthreads();   // drains vmcnt for global_load_lds

        short8 af[4], bfr[4];
        #pragma unroll
        for (int mt = 0; mt < 4; ++mt)
            af[mt] = *(const short8*)(sA + (wm0 + mt * 16 + ml) * 32 + quad * 8);
        #pragma unroll
        for (int nt = 0; nt < 4; ++nt)
            bfr[nt] = *(const short8*)(sB + (wn0 + nt * 16 + ml) * 32 + quad * 8);

        #pragma unroll
        for (int mt = 0; mt < 4; ++mt)
            #pragma unroll
            for (int nt = 0; nt < 4; ++nt)
                acc[mt][nt] = __builtin_amdgcn_mfma_f32_16x16x32_bf16(
                    af[mt], bfr[nt], acc[mt][nt], 0, 0, 0);
        __syncthreads();
    }

    // C/D layout: col = lane&15, row = quad*4 + reg
    #pragma unroll
    for (int mt = 0; mt < 4; ++mt)
        #pragma unroll
        for (int nt = 0; nt < 4; ++nt) {
            const int col = n0 + wn0 + nt * 16 + ml;
            #pragma unroll
            for (int r = 0; r < 4; ++r) {
                const int row = m0 + wm0 + mt * 16 + quad * 4 + r;
                if (BF16OUT)
                    ((short*)Cout)[(size_t)row * N + col] = f2bf(acc[mt][nt][r]);
                else
                    ((float*)Cout)[(size_t)row * N + col] = acc[mt][nt][r];
            }
        }
}

// Ut[s*128+d][h*128+dp] = cw[h]*scale * sum_{i<256} kb[s*256+i][h*128+dp]*vb[s*256+i][h*128+d]
// grid (16 sets, 8 heads, 4 quadrants), block 256; each block 64x64 of the 128x128 tile.
__global__ __launch_bounds__(256)
void build_u(const short* __restrict__ kb, const short* __restrict__ vb,
             const float* __restrict__ cw, short* __restrict__ Ut) {
    const int s = blockIdx.x, h = blockIdx.y, qd = blockIdx.z;
    const int dpoff = (qd >> 1) * 64, doff = (qd & 1) * 64;

    __shared__ float sK[32][64];
    __shared__ float sV[32][64];

    const int tid = threadIdx.x;
    const int tx = tid & 15, ty = tid >> 4;   // tx -> d, ty -> dp
    const int r = tid >> 3, c = (tid & 7) * 8;

    float acc[4][4];
    #pragma unroll
    for (int a = 0; a < 4; ++a)
        #pragma unroll
        for (int b = 0; b < 4; ++b) acc[a][b] = 0.f;

    for (int i0 = 0; i0 < 256; i0 += 32) {
        const size_t rowb = (size_t)(s * 256 + i0 + r) * 1024 + h * 128;
        const uint4 pk = *(const uint4*)(kb + rowb + dpoff + c);
        const uint4 pv = *(const uint4*)(vb + rowb + doff + c);
        const unsigned wk[4] = {pk.x, pk.y, pk.z, pk.w};
        const unsigned wv[4] = {pv.x, pv.y, pv.z, pv.w};
        #pragma unroll
        for (int u = 0; u < 4; ++u) {
            sK[r][c + 2 * u]     = bfbits2f(wk[u] << 16);
            sK[r][c + 2 * u + 1] = bfbits2f(wk[u] & 0xFFFF0000u);
            sV[r][c + 2 * u]     = bfbits2f(wv[u] << 16);
            sV[r][c + 2 * u + 1] = bfbits2f(wv[u] & 0xFFFF0000u);
        }
        __syncthreads();

        #pragma unroll 8
        for (int i = 0; i < 32; ++i) {
            float ka[4], va[4];
            *(float4*)ka = *(const float4*)&sK[i][ty * 4];
            *(float4*)va = *(const float4*)&sV[i][tx * 4];
            #pragma unroll
            for (int a = 0; a < 4; ++a)
                #pragma unroll
                for (int b = 0; b < 4; ++b)
                    acc[a][b] += ka[a] * va[b];
        }
        __syncthreads();
    }

    const float scale = cw[h] * (0.08838834764831845f / 256.0f);
    #pragma unroll
    for (int b = 0; b < 4; ++b) {
        short4 o;
        o.x = f2bf(acc[0][b] * scale);
        o.y = f2bf(acc[1][b] * scale);
        o.z = f2bf(acc[2][b] * scale);
        o.w = f2bf(acc[3][b] * scale);
        *(short4*)(Ut + (size_t)(s * 128 + doff + tx * 4 + b) * 1024
                       + h * 128 + dpoff + ty * 4) = o;
    }
}

extern "C" void kernel_launch(void* const* d_in, const int* in_sizes, int n_in,
                              void* d_out, int out_size, void* d_ws, size_t ws_size,
                              hipStream_t stream) {
    const float* x  = (const float*)d_in[0];  // [4096, 512]
    const float* y  = (const float*)d_in[1];  // [4096, 512]
    const float* W1 = (const float*)d_in[2];  // [512, 1024]
    const float* W2 = (const float*)d_in[3];
    const float* W3 = (const float*)d_in[4];
    const float* cw = (const float*)d_in[5];  // [8]
    float* out = (float*)d_out;               // [4096, 16, 128]

    short* xb  = (short*)d_ws;                        // 4096*512
    short* yb  = xb + (size_t)4096 * 512;
    short* w1t = yb + (size_t)4096 * 512;             // 1024*512 each
    short* w2t = w1t + (size_t)1024 * 512;
    short* w3t = w2t + (size_t)1024 * 512;
    short* qb  = w3t + (size_t)1024 * 512;            // 4096*1024 each
    short* kb  = qb + (size_t)4096 * 1024;
    short* vb  = kb + (size_t)4096 * 1024;
    short* Ut  = vb + (size_t)4096 * 1024;            // 2048*1024

    cvt_bf16<<<1024, 256, 0, stream>>>(x, xb, 4096 * 512 / 8);
    cvt_bf16<<<1024, 256, 0, stream>>>(y, yb, 4096 * 512 / 8);

    transpose_cvt<<<dim3(32, 16), dim3(32, 8), 0, stream>>>(W1, w1t, 512, 1024);
    transpose_cvt<<<dim3(32, 16), dim3(32, 8), 0, stream>>>(W2, w2t, 512, 1024);
    transpose_cvt<<<dim3(32, 16), dim3(32, 8), 0, stream>>>(W3, w3t, 512, 1024);

    gemm_bt<true><<<dim3(8, 32), 256, 0, stream>>>(xb, w1t, qb, 4096, 1024, 512);
    gemm_bt<true><<<dim3(8, 32), 256, 0, stream>>>(yb, w2t, kb, 4096, 1024, 512);
    gemm_bt<true><<<dim3(8, 32), 256, 0, stream>>>(yb, w3t, vb, 4096, 1024, 512);

    build_u<<<dim3(16, 8, 4), 256, 0, stream>>>(kb, vb, cw, Ut);

    gemm_bt<false><<<dim3(16, 32), 256, 0, stream>>>(qb, Ut, out, 4096, 2048, 1024);
}

// Round 3
// 159.763 us; speedup vs baseline: 3.2701x; 1.1888x over previous
//
#include <hip/hip_runtime.h>
#include <stdint.h>
#include <stddef.h>

// ---------------------------------------------------------------------------
// cseft reassociated (no [H,N,N] scores):
//   1. xb = bf16(x), yb = bf16(y)                       [one kernel]
//   2. w1t = bf16(W1^T) [1024,512]; w23t = bf16([W2|W3]^T) [2048,512]  [one kernel]
//   3. kvb = yb @ w23t   (bf16 MFMA, bf16 out) [4096,2048]  (k cols 0..1023, v 1024..2047)
//   4. fused: qb = xb @ w1t [4096,1024]  +  build Ut[2048,1024] from kvb   [one kernel]
//   5. out = qb @ Ut^T   (bf16 MFMA, fp32 out) [4096,2048]
// N=4096 K=512 H=8 Dh=128 nItem=256 nSet=16 hardcoded.
// ---------------------------------------------------------------------------

typedef short short8 __attribute__((ext_vector_type(8)));
typedef float f32x4 __attribute__((ext_vector_type(4)));

#define AS1 __attribute__((address_space(1)))
#define AS3 __attribute__((address_space(3)))

__device__ __forceinline__ void gl_lds16(const void* g, void* l) {
    __builtin_amdgcn_global_load_lds((AS1 void*)(uintptr_t)g, (AS3 void*)l, 16, 0, 0);
}

__device__ __forceinline__ short f2bf(float f) {
    union { float f; unsigned u; } v; v.f = f;
    unsigned r = v.u + 0x7FFFu + ((v.u >> 16) & 1u);
    return (short)(r >> 16);
}
__device__ __forceinline__ float bfbits2f(unsigned hi_bits) {
    union { unsigned u; float f; } v; v.u = hi_bits; return v.f;
}

// fp32 -> bf16, 8 elems/thread. blocks 0..1023: x (262144 groups), 1024..2047: y.
__global__ __launch_bounds__(256)
void cvt_bf16_xy(const float* __restrict__ x, const float* __restrict__ y,
                 short* __restrict__ xb, short* __restrict__ yb) {
    const int b = blockIdx.x;
    const float* in  = (b < 1024) ? x  : y;
    short*       out = (b < 1024) ? xb : yb;
    const int i = (b & 1023) * 256 + threadIdx.x;   // 0..262143
    const float4* p = (const float4*)in + (size_t)i * 2;
    float4 a = p[0], c = p[1];
    short8 o;
    o[0] = f2bf(a.x); o[1] = f2bf(a.y); o[2] = f2bf(a.z); o[3] = f2bf(a.w);
    o[4] = f2bf(c.x); o[5] = f2bf(c.y); o[6] = f2bf(c.z); o[7] = f2bf(c.w);
    *((short8*)out + i) = o;
}

// W[512][1024] fp32 -> Wt[1024][512] bf16. grid (32,16,3): z=0 W1->w1t,
// z=1 W2->w23t rows 0..1023, z=2 W3->w23t rows 1024..2047. block (32,8).
__global__ __launch_bounds__(256)
void transpose_cvt3(const float* __restrict__ W1, const float* __restrict__ W2,
                    const float* __restrict__ W3, short* __restrict__ w1t,
                    short* __restrict__ w23t) {
    __shared__ float t[32][33];
    const int z = blockIdx.z;
    const float* W  = (z == 0) ? W1 : (z == 1) ? W2 : W3;
    short*      Wt  = (z == 0) ? w1t : (z == 1) ? w23t : (w23t + (size_t)1024 * 512);
    const int bx = blockIdx.x * 32, by = blockIdx.y * 32;
    const int tx = threadIdx.x, ty = threadIdx.y;
    #pragma unroll
    for (int j = 0; j < 4; ++j)
        t[ty + j * 8][tx] = W[(size_t)(by + ty + j * 8) * 1024 + bx + tx];
    __syncthreads();
    #pragma unroll
    for (int j = 0; j < 4; ++j)
        Wt[(size_t)(bx + ty + j * 8) * 512 + by + tx] = f2bf(t[tx][ty + j * 8]);
}

// --- device-side 128x128 MFMA gemm tile: C = A[M,K] * Bt[N,K]^T -------------
// 256 thr = 4 waves, each wave 64x64 via 4x4 of 16x16x32 MFMA. smem: 16 KB.
template <bool BF16OUT>
__device__ __forceinline__
void gemm_tile(const short* __restrict__ A, const short* __restrict__ Bt,
               void* __restrict__ Cout, int N, int K, int bx, int by,
               char* smem) {
    short* sA = (short*)smem;             // 128*32
    short* sB = (short*)(smem + 8192);    // 128*32

    const int tid = threadIdx.x;
    const int wave = tid >> 6, lane = tid & 63;
    const int quad = lane >> 4, ml = lane & 15;
    const int m0 = by * 128, n0 = bx * 128;
    const int wm0 = (wave >> 1) * 64, wn0 = (wave & 1) * 64;
    const int srow = lane >> 2, skoff = (lane & 3) * 8;
    const int c0 = 2 * wave, c1 = 2 * wave + 1;

    f32x4 acc[4][4];
    #pragma unroll
    for (int i = 0; i < 4; ++i)
        #pragma unroll
        for (int j = 0; j < 4; ++j) {
            acc[i][j][0] = 0.f; acc[i][j][1] = 0.f;
            acc[i][j][2] = 0.f; acc[i][j][3] = 0.f;
        }

    for (int kt = 0; kt < K; kt += 32) {
        gl_lds16(A  + (size_t)(m0 + c0 * 16 + srow) * K + kt + skoff,
                 (char*)sA + c0 * 1024 + lane * 16);
        gl_lds16(A  + (size_t)(m0 + c1 * 16 + srow) * K + kt + skoff,
                 (char*)sA + c1 * 1024 + lane * 16);
        gl_lds16(Bt + (size_t)(n0 + c0 * 16 + srow) * K + kt + skoff,
                 (char*)sB + c0 * 1024 + lane * 16);
        gl_lds16(Bt + (size_t)(n0 + c1 * 16 + srow) * K + kt + skoff,
                 (char*)sB + c1 * 1024 + lane * 16);
        __syncthreads();

        short8 af[4], bfr[4];
        #pragma unroll
        for (int mt = 0; mt < 4; ++mt)
            af[mt] = *(const short8*)(sA + (wm0 + mt * 16 + ml) * 32 + quad * 8);
        #pragma unroll
        for (int nt = 0; nt < 4; ++nt)
            bfr[nt] = *(const short8*)(sB + (wn0 + nt * 16 + ml) * 32 + quad * 8);

        #pragma unroll
        for (int mt = 0; mt < 4; ++mt)
            #pragma unroll
            for (int nt = 0; nt < 4; ++nt)
                acc[mt][nt] = __builtin_amdgcn_mfma_f32_16x16x32_bf16(
                    af[mt], bfr[nt], acc[mt][nt], 0, 0, 0);
        __syncthreads();
    }

    // C/D layout: col = lane&15, row = quad*4 + reg
    #pragma unroll
    for (int mt = 0; mt < 4; ++mt)
        #pragma unroll
        for (int nt = 0; nt < 4; ++nt) {
            const int col = n0 + wn0 + nt * 16 + ml;
            #pragma unroll
            for (int r = 0; r < 4; ++r) {
                const int row = m0 + wm0 + mt * 16 + quad * 4 + r;
                if (BF16OUT)
                    ((short*)Cout)[(size_t)row * N + col] = f2bf(acc[mt][nt][r]);
                else
                    ((float*)Cout)[(size_t)row * N + col] = acc[mt][nt][r];
            }
        }
}

// kv GEMM: kvb[4096,2048] = yb @ w23t^T. grid (16,32).
__global__ __launch_bounds__(256)
void gemm_kv(const short* __restrict__ yb, const short* __restrict__ w23t,
             short* __restrict__ kvb) {
    __shared__ char smem[16384];
    gemm_tile<true>(yb, w23t, kvb, 2048, 512, blockIdx.x, blockIdx.y, smem);
}

// Fused: blocks 0..255 -> q GEMM tiles (qb = xb @ w1t^T, [4096,1024]);
//        blocks 256..767 -> build_u 64x64 tiles (Ut from kvb).
// build_u: Ut[s*128+d][h*128+dp] = cw[h]*scale * sum_i kvb[s*256+i][h*128+dp]
//                                                   * kvb[s*256+i][1024+h*128+d]
__global__ __launch_bounds__(256)
void fused_q_bu(const short* __restrict__ xb, const short* __restrict__ w1t,
                short* __restrict__ qb, const short* __restrict__ kvb,
                const float* __restrict__ cw, short* __restrict__ Ut) {
    __shared__ char smem[16384];
    const int b = blockIdx.x;
    if (b < 256) {
        gemm_tile<true>(xb, w1t, qb, 1024, 512, b & 7, b >> 3, smem);
        return;
    }
    const int b2 = b - 256;                 // 0..511
    const int s = b2 & 15, h = (b2 >> 4) & 7, qd = b2 >> 7;
    const int dpoff = (qd >> 1) * 64, doff = (qd & 1) * 64;

    float (*sK)[64] = (float(*)[64])smem;            // 32x64 f32 = 8 KB
    float (*sV)[64] = (float(*)[64])(smem + 8192);   // 32x64 f32 = 8 KB

    const int tid = threadIdx.x;
    const int tx = tid & 15, ty = tid >> 4;   // tx -> d, ty -> dp
    const int r = tid >> 3, c = (tid & 7) * 8;

    float acc[4][4];
    #pragma unroll
    for (int a = 0; a < 4; ++a)
        #pragma unroll
        for (int bb = 0; bb < 4; ++bb) acc[a][bb] = 0.f;

    for (int i0 = 0; i0 < 256; i0 += 32) {
        const size_t rowb = (size_t)(s * 256 + i0 + r) * 2048 + h * 128;
        const uint4 pk = *(const uint4*)(kvb + rowb + dpoff + c);
        const uint4 pv = *(const uint4*)(kvb + rowb + 1024 + doff + c);
        const unsigned wk[4] = {pk.x, pk.y, pk.z, pk.w};
        const unsigned wv[4] = {pv.x, pv.y, pv.z, pv.w};
        #pragma unroll
        for (int u = 0; u < 4; ++u) {
            sK[r][c + 2 * u]     = bfbits2f(wk[u] << 16);
            sK[r][c + 2 * u + 1] = bfbits2f(wk[u] & 0xFFFF0000u);
            sV[r][c + 2 * u]     = bfbits2f(wv[u] << 16);
            sV[r][c + 2 * u + 1] = bfbits2f(wv[u] & 0xFFFF0000u);
        }
        __syncthreads();

        #pragma unroll 8
        for (int i = 0; i < 32; ++i) {
            float ka[4], va[4];
            *(float4*)ka = *(const float4*)&sK[i][ty * 4];
            *(float4*)va = *(const float4*)&sV[i][tx * 4];
            #pragma unroll
            for (int a = 0; a < 4; ++a)
                #pragma unroll
                for (int bb = 0; bb < 4; ++bb)
                    acc[a][bb] += ka[a] * va[bb];
        }
        __syncthreads();
    }

    const float scale = cw[h] * (0.08838834764831845f / 256.0f);
    #pragma unroll
    for (int bb = 0; bb < 4; ++bb) {
        short4 o;
        o.x = f2bf(acc[0][bb] * scale);
        o.y = f2bf(acc[1][bb] * scale);
        o.z = f2bf(acc[2][bb] * scale);
        o.w = f2bf(acc[3][bb] * scale);
        *(short4*)(Ut + (size_t)(s * 128 + doff + tx * 4 + bb) * 1024
                       + h * 128 + dpoff + ty * 4) = o;
    }
}

// Final: out[4096,2048] = qb @ Ut^T, fp32 out. grid (16,32).
__global__ __launch_bounds__(256)
void gemm_out(const short* __restrict__ qb, const short* __restrict__ Ut,
              float* __restrict__ out) {
    __shared__ char smem[16384];
    gemm_tile<false>(qb, Ut, out, 2048, 1024, blockIdx.x, blockIdx.y, smem);
}

extern "C" void kernel_launch(void* const* d_in, const int* in_sizes, int n_in,
                              void* d_out, int out_size, void* d_ws, size_t ws_size,
                              hipStream_t stream) {
    const float* x  = (const float*)d_in[0];  // [4096, 512]
    const float* y  = (const float*)d_in[1];  // [4096, 512]
    const float* W1 = (const float*)d_in[2];  // [512, 1024]
    const float* W2 = (const float*)d_in[3];
    const float* W3 = (const float*)d_in[4];
    const float* cw = (const float*)d_in[5];  // [8]
    float* out = (float*)d_out;               // [4096, 16, 128]

    short* xb   = (short*)d_ws;                       // 4096*512
    short* yb   = xb   + (size_t)4096 * 512;
    short* w1t  = yb   + (size_t)4096 * 512;          // 1024*512
    short* w23t = w1t  + (size_t)1024 * 512;          // 2048*512
    short* qb   = w23t + (size_t)2048 * 512;          // 4096*1024
    short* kvb  = qb   + (size_t)4096 * 1024;         // 4096*2048
    short* Ut   = kvb  + (size_t)4096 * 2048;         // 2048*1024

    cvt_bf16_xy<<<2048, 256, 0, stream>>>(x, y, xb, yb);
    transpose_cvt3<<<dim3(32, 16, 3), dim3(32, 8), 0, stream>>>(W1, W2, W3, w1t, w23t);
    gemm_kv<<<dim3(16, 32), 256, 0, stream>>>(yb, w23t, kvb);
    fused_q_bu<<<768, 256, 0, stream>>>(xb, w1t, qb, kvb, cw, Ut);
    gemm_out<<<dim3(16, 32), 256, 0, stream>>>(qb, Ut, out);
}

// Round 4
// 155.869 us; speedup vs baseline: 3.3518x; 1.0250x over previous
//
#include <hip/hip_runtime.h>
#include <stdint.h>
#include <stddef.h>

// ---------------------------------------------------------------------------
// cseft reassociated twice (no [H,N,N] scores, no qb intermediate):
//   1. prep: xb=bf16(x), yb=bf16(y), w1b=bf16(W1) [512,1024],
//            w23t=bf16([W2|W3]^T) [2048,512]                      [one kernel]
//   2. kvb = yb @ w23t^T   (MFMA, bf16 out) [4096,2048]
//   3. Ut[s*128+d][h*128+dp] = cw[h]*scale * sum_i k*v   (VALU)   [2048,1024]
//   4. G = Ut @ w1b^T      (MFMA, bf16 out) [2048,512]   (folds W1 into U)
//   5. out = xb @ G^T      (MFMA, fp32 out) [4096,2048]
// Total MFMA work: 8.6 + 2.1 + 8.6 = 19.3 GF (was 30 GF with qb).
// N=4096 K=512 H=8 Dh=128 nItem=256 nSet=16 hardcoded.
// ---------------------------------------------------------------------------

typedef short short8 __attribute__((ext_vector_type(8)));
typedef float f32x4 __attribute__((ext_vector_type(4)));

#define AS1 __attribute__((address_space(1)))
#define AS3 __attribute__((address_space(3)))

__device__ __forceinline__ void gl_lds16(const void* g, void* l) {
    __builtin_amdgcn_global_load_lds((AS1 void*)(uintptr_t)g, (AS3 void*)l, 16, 0, 0);
}

__device__ __forceinline__ short f2bf(float f) {
    union { float f; unsigned u; } v; v.f = f;
    unsigned r = v.u + 0x7FFFu + ((v.u >> 16) & 1u);
    return (short)(r >> 16);
}
__device__ __forceinline__ float bfbits2f(unsigned hi_bits) {
    union { unsigned u; float f; } v; v.u = hi_bits; return v.f;
}

// --- fused prep: blocks 0..1023 x->xb, 1024..2047 y->yb, 2048..2303 W1->w1b,
//     2304..2815 W2->w23t[0:1024], 2816..3327 W3->w23t[1024:2048] (transposed)
__global__ __launch_bounds__(256)
void prep(const float* __restrict__ x, const float* __restrict__ y,
          const float* __restrict__ W1, const float* __restrict__ W2,
          const float* __restrict__ W3, short* __restrict__ xb,
          short* __restrict__ yb, short* __restrict__ w1b,
          short* __restrict__ w23t) {
    const int b = blockIdx.x, tid = threadIdx.x;
    __shared__ float t[32][33];
    if (b < 2304) {
        const float* in; short* out; int i;
        if (b < 1024)      { in = x;  out = xb;  i = b * 256 + tid; }
        else if (b < 2048) { in = y;  out = yb;  i = (b - 1024) * 256 + tid; }
        else               { in = W1; out = w1b; i = (b - 2048) * 256 + tid; }
        const float4* p = (const float4*)in + (size_t)i * 2;
        float4 a = p[0], c4 = p[1];
        short8 o;
        o[0] = f2bf(a.x);  o[1] = f2bf(a.y);  o[2] = f2bf(a.z);  o[3] = f2bf(a.w);
        o[4] = f2bf(c4.x); o[5] = f2bf(c4.y); o[6] = f2bf(c4.z); o[7] = f2bf(c4.w);
        *((short8*)out + i) = o;
        return;
    }
    const int b2 = b - 2304;                 // 0..1023
    const int z  = b2 >> 9;                  // 0: W2, 1: W3
    const int b3 = b2 & 511;
    const float* W = z ? W3 : W2;
    short* Wt = w23t + (size_t)z * 1024 * 512;
    const int bx = (b3 & 31) * 32, by = (b3 >> 5) * 32;
    const int tx = tid & 31, ty = tid >> 5;
    #pragma unroll
    for (int j = 0; j < 4; ++j)
        t[ty + j * 8][tx] = W[(size_t)(by + ty + j * 8) * 1024 + bx + tx];
    __syncthreads();
    #pragma unroll
    for (int j = 0; j < 4; ++j)
        Wt[(size_t)(bx + ty + j * 8) * 512 + by + tx] = f2bf(t[tx][ty + j * 8]);
}

// --- generic MFMA tile: C[BMxBN] = A[M,K] * Bt[N,K]^T, 4 waves (WM x WN) ----
template <int BM, int BN, int WM, int WN, bool BF16OUT>
__device__ __forceinline__
void gemm_tile(const short* __restrict__ A, const short* __restrict__ Bt,
               void* __restrict__ Cout, int N, int K, int bx, int by,
               char* smem) {
    constexpr int MT = BM / WM / 16;         // m-frags per wave
    constexpr int NT = BN / WN / 16;         // n-frags per wave
    constexpr int NCA = BM / 16, NCB = BN / 16;
    short* sA = (short*)smem;                // BM x 32
    short* sB = (short*)(smem + BM * 64);    // BN x 32

    const int tid = threadIdx.x;
    const int wave = tid >> 6, lane = tid & 63;
    const int quad = lane >> 4, ml = lane & 15;
    const int m0 = by * BM, n0 = bx * BN;
    const int wm0 = (wave / WN) * (BM / WM);
    const int wn0 = (wave % WN) * (BN / WN);
    const int srow = lane >> 2, skoff = (lane & 3) * 8;

    f32x4 acc[MT][NT];
    #pragma unroll
    for (int i = 0; i < MT; ++i)
        #pragma unroll
        for (int j = 0; j < NT; ++j) {
            acc[i][j][0] = 0.f; acc[i][j][1] = 0.f;
            acc[i][j][2] = 0.f; acc[i][j][3] = 0.f;
        }

    for (int kt = 0; kt < K; kt += 32) {
        #pragma unroll
        for (int ci = 0; ci < (NCA + NCB) / 4; ++ci) {
            const int c = wave + ci * 4;
            if (c < NCA)
                gl_lds16(A + (size_t)(m0 + c * 16 + srow) * K + kt + skoff,
                         (char*)sA + c * 1024 + lane * 16);
            else
                gl_lds16(Bt + (size_t)(n0 + (c - NCA) * 16 + srow) * K + kt + skoff,
                         (char*)sB + (c - NCA) * 1024 + lane * 16);
        }
        __syncthreads();   // drains vmcnt for global_load_lds

        short8 af[MT], bfr[NT];
        #pragma unroll
        for (int mt = 0; mt < MT; ++mt)
            af[mt] = *(const short8*)(sA + (wm0 + mt * 16 + ml) * 32 + quad * 8);
        #pragma unroll
        for (int nt = 0; nt < NT; ++nt)
            bfr[nt] = *(const short8*)(sB + (wn0 + nt * 16 + ml) * 32 + quad * 8);

        #pragma unroll
        for (int mt = 0; mt < MT; ++mt)
            #pragma unroll
            for (int nt = 0; nt < NT; ++nt)
                acc[mt][nt] = __builtin_amdgcn_mfma_f32_16x16x32_bf16(
                    af[mt], bfr[nt], acc[mt][nt], 0, 0, 0);
        __syncthreads();
    }

    // C/D layout: col = lane&15, row = quad*4 + reg
    #pragma unroll
    for (int mt = 0; mt < MT; ++mt)
        #pragma unroll
        for (int nt = 0; nt < NT; ++nt) {
            const int col = n0 + wn0 + nt * 16 + ml;
            #pragma unroll
            for (int r = 0; r < 4; ++r) {
                const int row = m0 + wm0 + mt * 16 + quad * 4 + r;
                if (BF16OUT)
                    ((short*)Cout)[(size_t)row * N + col] = f2bf(acc[mt][nt][r]);
                else
                    ((float*)Cout)[(size_t)row * N + col] = acc[mt][nt][r];
            }
        }
}

// kvb[4096,2048] = yb @ w23t^T. grid (16,32).
__global__ __launch_bounds__(256)
void gemm_kv(const short* __restrict__ yb, const short* __restrict__ w23t,
             short* __restrict__ kvb) {
    __shared__ char smem[16384];
    gemm_tile<128, 128, 2, 2, true>(yb, w23t, kvb, 2048, 512,
                                    blockIdx.x, blockIdx.y, smem);
}

// Ut[s*128+d][h*128+dp] = cw[h]*scale * sum_i kvb[s*256+i][h*128+dp]
//                                            * kvb[s*256+i][1024+h*128+d]
// grid (16,8,4): 64x64 quadrant per block.
__global__ __launch_bounds__(256)
void build_u(const short* __restrict__ kvb, const float* __restrict__ cw,
             short* __restrict__ Ut) {
    const int s = blockIdx.x, h = blockIdx.y, qd = blockIdx.z;
    const int dpoff = (qd >> 1) * 64, doff = (qd & 1) * 64;

    __shared__ float sK[32][64];
    __shared__ float sV[32][64];

    const int tid = threadIdx.x;
    const int tx = tid & 15, ty = tid >> 4;   // tx -> d, ty -> dp
    const int r = tid >> 3, c = (tid & 7) * 8;

    float acc[4][4];
    #pragma unroll
    for (int a = 0; a < 4; ++a)
        #pragma unroll
        for (int bb = 0; bb < 4; ++bb) acc[a][bb] = 0.f;

    for (int i0 = 0; i0 < 256; i0 += 32) {
        const size_t rowb = (size_t)(s * 256 + i0 + r) * 2048 + h * 128;
        const uint4 pk = *(const uint4*)(kvb + rowb + dpoff + c);
        const uint4 pv = *(const uint4*)(kvb + rowb + 1024 + doff + c);
        const unsigned wk[4] = {pk.x, pk.y, pk.z, pk.w};
        const unsigned wv[4] = {pv.x, pv.y, pv.z, pv.w};
        #pragma unroll
        for (int u = 0; u < 4; ++u) {
            sK[r][c + 2 * u]     = bfbits2f(wk[u] << 16);
            sK[r][c + 2 * u + 1] = bfbits2f(wk[u] & 0xFFFF0000u);
            sV[r][c + 2 * u]     = bfbits2f(wv[u] << 16);
            sV[r][c + 2 * u + 1] = bfbits2f(wv[u] & 0xFFFF0000u);
        }
        __syncthreads();

        #pragma unroll 8
        for (int i = 0; i < 32; ++i) {
            float ka[4], va[4];
            *(float4*)ka = *(const float4*)&sK[i][ty * 4];
            *(float4*)va = *(const float4*)&sV[i][tx * 4];
            #pragma unroll
            for (int a = 0; a < 4; ++a)
                #pragma unroll
                for (int bb = 0; bb < 4; ++bb)
                    acc[a][bb] += ka[a] * va[bb];
        }
        __syncthreads();
    }

    const float scale = cw[h] * (0.08838834764831845f / 256.0f);
    #pragma unroll
    for (int bb = 0; bb < 4; ++bb) {
        short4 o;
        o.x = f2bf(acc[0][bb] * scale);
        o.y = f2bf(acc[1][bb] * scale);
        o.z = f2bf(acc[2][bb] * scale);
        o.w = f2bf(acc[3][bb] * scale);
        *(short4*)(Ut + (size_t)(s * 128 + doff + tx * 4 + bb) * 1024
                       + h * 128 + dpoff + ty * 4) = o;
    }
}

// G[2048,512] = Ut @ w1b^T  (A=Ut [2048,1024], Bt=w1b [512,1024]). grid (4,32).
__global__ __launch_bounds__(256)
void gemm_g(const short* __restrict__ Ut, const short* __restrict__ w1b,
            short* __restrict__ G) {
    __shared__ char smem[12288];
    gemm_tile<64, 128, 2, 2, true>(Ut, w1b, G, 512, 1024,
                                   blockIdx.x, blockIdx.y, smem);
}

// out[4096,2048] = xb @ G^T, fp32 out. grid (16,32).
__global__ __launch_bounds__(256)
void gemm_out(const short* __restrict__ xb, const short* __restrict__ G,
              float* __restrict__ out) {
    __shared__ char smem[16384];
    gemm_tile<128, 128, 2, 2, false>(xb, G, out, 2048, 512,
                                     blockIdx.x, blockIdx.y, smem);
}

extern "C" void kernel_launch(void* const* d_in, const int* in_sizes, int n_in,
                              void* d_out, int out_size, void* d_ws, size_t ws_size,
                              hipStream_t stream) {
    const float* x  = (const float*)d_in[0];  // [4096, 512]
    const float* y  = (const float*)d_in[1];  // [4096, 512]
    const float* W1 = (const float*)d_in[2];  // [512, 1024]
    const float* W2 = (const float*)d_in[3];
    const float* W3 = (const float*)d_in[4];
    const float* cw = (const float*)d_in[5];  // [8]
    float* out = (float*)d_out;               // [4096, 16, 128]

    short* xb   = (short*)d_ws;                       // 4096*512
    short* yb   = xb   + (size_t)4096 * 512;
    short* w1b  = yb   + (size_t)4096 * 512;          // 512*1024 (NOT transposed)
    short* w23t = w1b  + (size_t)512 * 1024;          // 2048*512 (transposed)
    short* kvb  = w23t + (size_t)2048 * 512;          // 4096*2048
    short* Ut   = kvb  + (size_t)4096 * 2048;         // 2048*1024
    short* G    = Ut   + (size_t)2048 * 1024;         // 2048*512

    prep<<<3328, 256, 0, stream>>>(x, y, W1, W2, W3, xb, yb, w1b, w23t);
    gemm_kv<<<dim3(16, 32), 256, 0, stream>>>(yb, w23t, kvb);
    build_u<<<dim3(16, 8, 4), 256, 0, stream>>>(kvb, cw, Ut);
    gemm_g<<<dim3(4, 32), 256, 0, stream>>>(Ut, w1b, G);
    gemm_out<<<dim3(16, 32), 256, 0, stream>>>(xb, G, out);
}

// Round 6
// 141.647 us; speedup vs baseline: 3.6883x; 1.1004x over previous
//
#include <hip/hip_runtime.h>
#include <stdint.h>
#include <stddef.h>

// ---------------------------------------------------------------------------
// cseft reassociated (no [H,N,N] scores). 4 launches:
//   1. prep:  xb=bf16(x), yb=bf16(y), w1t=bf16(W1^T) [1024,512],
//             w23t=bf16([W2|W3]^T) [2048,512]
//   2. stageB: kvt[2048,4096] = w23t @ yb^T  (rows 0..1023 k-ch, 1024.. v-ch)
//              qb [4096,1024] = xb @ w1t^T        (both MFMA, bf16 out)
//   3. build_u (MFMA): Ut[s*128+d][h*128+dp] =
//              cw[h]*sc * sum_i kvt[1024+h*128+d][s*256+i]*kvt[h*128+dp][s*256+i]
//   4. out[4096,2048] = qb @ Ut^T  (MFMA, fp32 out)
// N=4096 K=512 H=8 Dh=128 nItem=256 nSet=16 hardcoded.
// ---------------------------------------------------------------------------

typedef short short8 __attribute__((ext_vector_type(8)));
typedef float f32x4 __attribute__((ext_vector_type(4)));

#define AS1 __attribute__((address_space(1)))
#define AS3 __attribute__((address_space(3)))

__device__ __forceinline__ void gl_lds16(const void* g, void* l) {
    __builtin_amdgcn_global_load_lds((AS1 void*)(uintptr_t)g, (AS3 void*)l, 16, 0, 0);
}

__device__ __forceinline__ short f2bf(float f) {
    union { float f; unsigned u; } v; v.f = f;
    unsigned r = v.u + 0x7FFFu + ((v.u >> 16) & 1u);
    return (short)(r >> 16);
}

// --- prep: 0..1023 x->xb, 1024..2047 y->yb, 2048..3071 W2/W3->w23t (T),
//     3072..3583 W1->w1t (T). 3584 blocks x 256 thr.
__global__ __launch_bounds__(256)
void prep(const float* __restrict__ x, const float* __restrict__ y,
          const float* __restrict__ W1, const float* __restrict__ W2,
          const float* __restrict__ W3, short* __restrict__ xb,
          short* __restrict__ yb, short* __restrict__ w1t,
          short* __restrict__ w23t) {
    const int b = blockIdx.x, tid = threadIdx.x;
    if (b < 2048) {
        const float* in = (b < 1024) ? x : y;
        short* o = (b < 1024) ? xb : yb;
        const int i = (b & 1023) * 256 + tid;
        const float4* p = (const float4*)in + (size_t)i * 2;
        float4 a = p[0], c4 = p[1];
        short8 s8;
        s8[0] = f2bf(a.x);  s8[1] = f2bf(a.y);
        s8[2] = f2bf(a.z);  s8[3] = f2bf(a.w);
        s8[4] = f2bf(c4.x); s8[5] = f2bf(c4.y);
        s8[6] = f2bf(c4.z); s8[7] = f2bf(c4.w);
        *((short8*)o + i) = s8;
        return;
    }
    __shared__ float t[32][33];
    const float* W; short* Wt; int b3;
    if (b < 3072) {
        const int b2 = b - 2048;                 // 0..1023
        const int z = b2 >> 9;                   // 0: W2, 1: W3
        W = z ? W3 : W2;
        Wt = w23t + (size_t)z * 1024 * 512;
        b3 = b2 & 511;
    } else {
        W = W1; Wt = w1t; b3 = b - 3072;         // 0..511
    }
    const int bx = (b3 & 31) * 32, by = (b3 >> 5) * 32;
    const int tx = tid & 31, ty = tid >> 5;
    #pragma unroll
    for (int j = 0; j < 4; ++j)
        t[ty + j * 8][tx] = W[(size_t)(by + ty + j * 8) * 1024 + bx + tx];
    __syncthreads();
    #pragma unroll
    for (int j = 0; j < 4; ++j)
        Wt[(size_t)(bx + ty + j * 8) * 512 + by + tx] = f2bf(t[tx][ty + j * 8]);
}

// --- generic MFMA tile: C[128x128] = A[.,K] * Bt[.,K]^T --------------------
// 4 waves in 2x2; OUTMODE: 0 = f32 store, 1 = bf16 store, 2 = bf16*scale.
template <int OUTMODE>
__device__ __forceinline__
void gemm_tile(const short* __restrict__ A, int lda,
               const short* __restrict__ Bt, int ldb,
               void* __restrict__ Cout, int ldc, int K,
               int bx, int by, float scale, char* smem) {
    short* sA = (short*)smem;                 // [128][32]
    short* sB = (short*)(smem + 8192);        // [128][32]

    const int tid = threadIdx.x;
    const int wave = tid >> 6, lane = tid & 63;
    const int quad = lane >> 4, ml = lane & 15;
    const int m0 = by * 128, n0 = bx * 128;
    const int wm0 = (wave >> 1) * 64, wn0 = (wave & 1) * 64;
    const int srow = lane >> 2, skoff = (lane & 3) * 8;

    f32x4 acc[4][4];
    #pragma unroll
    for (int i = 0; i < 4; ++i)
        #pragma unroll
        for (int j = 0; j < 4; ++j) {
            acc[i][j][0] = 0.f; acc[i][j][1] = 0.f;
            acc[i][j][2] = 0.f; acc[i][j][3] = 0.f;
        }

    for (int kt = 0; kt < K; kt += 32) {
        #pragma unroll
        for (int ci = 0; ci < 4; ++ci) {
            const int c = wave + ci * 4;
            if (c < 8)
                gl_lds16(A + (size_t)(m0 + c * 16 + srow) * lda + kt + skoff,
                         (char*)sA + c * 1024 + lane * 16);
            else
                gl_lds16(Bt + (size_t)(n0 + (c - 8) * 16 + srow) * ldb + kt + skoff,
                         (char*)sB + (c - 8) * 1024 + lane * 16);
        }
        __syncthreads();   // drains vmcnt for global_load_lds

        short8 af[4], bfr[4];
        #pragma unroll
        for (int mt = 0; mt < 4; ++mt)
            af[mt] = *(const short8*)(sA + (wm0 + mt * 16 + ml) * 32 + quad * 8);
        #pragma unroll
        for (int nt = 0; nt < 4; ++nt)
            bfr[nt] = *(const short8*)(sB + (wn0 + nt * 16 + ml) * 32 + quad * 8);

        #pragma unroll
        for (int mt = 0; mt < 4; ++mt)
            #pragma unroll
            for (int nt = 0; nt < 4; ++nt)
                acc[mt][nt] = __builtin_amdgcn_mfma_f32_16x16x32_bf16(
                    af[mt], bfr[nt], acc[mt][nt], 0, 0, 0);
        __syncthreads();
    }

    // C/D layout: col = lane&15, row = quad*4 + reg
    #pragma unroll
    for (int mt = 0; mt < 4; ++mt)
        #pragma unroll
        for (int nt = 0; nt < 4; ++nt) {
            const int col = n0 + wn0 + nt * 16 + ml;
            #pragma unroll
            for (int r = 0; r < 4; ++r) {
                const int row = m0 + wm0 + mt * 16 + quad * 4 + r;
                float v = acc[mt][nt][r];
                if (OUTMODE == 2) v *= scale;
                if (OUTMODE == 0)
                    ((float*)Cout)[(size_t)row * ldc + col] = v;
                else
                    ((short*)Cout)[(size_t)row * ldc + col] = f2bf(v);
            }
        }
}

// stage B: blocks 0..511 kvt tiles, 512..767 qb tiles.
__global__ __launch_bounds__(256)
void stage_b(const short* __restrict__ yb, const short* __restrict__ w23t,
             const short* __restrict__ xb, const short* __restrict__ w1t,
             short* __restrict__ kvt, short* __restrict__ qb) {
    __shared__ char smem[16384];
    const int b = blockIdx.x;
    if (b < 512) {
        // kvt[2048,4096] = w23t @ yb^T : m-tiles 16, n-tiles 32
        gemm_tile<1>(w23t, 512, yb, 512, kvt, 4096, 512,
                     b & 31, b >> 5, 1.f, smem);
    } else {
        // qb[4096,1024] = xb @ w1t^T : m-tiles 32, n-tiles 8
        const int b2 = b - 512;
        gemm_tile<1>(xb, 512, w1t, 512, qb, 1024, 512,
                     b2 & 7, b2 >> 3, 1.f, smem);
    }
}

// build_u: grid (16,8); Ut tile (s,h) = scale * V_rows @ K_rows^T, K=256.
__global__ __launch_bounds__(256)
void build_u(const short* __restrict__ kvt, const float* __restrict__ cw,
             short* __restrict__ Ut) {
    __shared__ char smem[16384];
    const int s = blockIdx.x, h = blockIdx.y;
    const float scale = cw[h] * (0.08838834764831845f / 256.0f);
    gemm_tile<2>(kvt + (size_t)(1024 + h * 128) * 4096 + s * 256, 4096,  // V: m=d
                 kvt + (size_t)(h * 128) * 4096 + s * 256, 4096,         // K: n=dp
                 Ut + (size_t)(s * 128) * 1024 + h * 128, 1024, 256,
                 0, 0, scale, smem);
}

// out[4096,2048] = qb @ Ut^T, fp32. grid (16,32).
__global__ __launch_bounds__(256)
void gemm_out(const short* __restrict__ qb, const short* __restrict__ Ut,
              float* __restrict__ out) {
    __shared__ char smem[16384];
    gemm_tile<0>(qb, 1024, Ut, 1024, out, 2048, 1024,
                 blockIdx.x, blockIdx.y, 1.f, smem);
}

extern "C" void kernel_launch(void* const* d_in, const int* in_sizes, int n_in,
                              void* d_out, int out_size, void* d_ws, size_t ws_size,
                              hipStream_t stream) {
    const float* x  = (const float*)d_in[0];  // [4096, 512]
    const float* y  = (const float*)d_in[1];  // [4096, 512]
    const float* W1 = (const float*)d_in[2];  // [512, 1024]
    const float* W2 = (const float*)d_in[3];
    const float* W3 = (const float*)d_in[4];
    const float* cw = (const float*)d_in[5];  // [8]
    float* out = (float*)d_out;               // [4096, 16, 128]

    short* xb   = (short*)d_ws;                       // 4096*512
    short* yb   = xb   + (size_t)4096 * 512;          // 4096*512
    short* w1t  = yb   + (size_t)4096 * 512;          // 1024*512 (transposed)
    short* w23t = w1t  + (size_t)1024 * 512;          // 2048*512 (transposed)
    short* kvt  = w23t + (size_t)2048 * 512;          // 2048*4096
    short* qb   = kvt  + (size_t)2048 * 4096;         // 4096*1024
    short* Ut   = qb   + (size_t)4096 * 1024;         // 2048*1024

    prep<<<3584, 256, 0, stream>>>(x, y, W1, W2, W3, xb, yb, w1t, w23t);
    stage_b<<<768, 256, 0, stream>>>(yb, w23t, xb, w1t, kvt, qb);
    build_u<<<dim3(16, 8), 256, 0, stream>>>(kvt, cw, Ut);
    gemm_out<<<dim3(16, 32), 256, 0, stream>>>(qb, Ut, out);
}